// Round 13
// baseline (133.081 us; speedup 1.0000x reference)
//
#include <hip/hip_runtime.h>

#define WF 512
#define HF 256
#define CF 64
#define NDTOT 65
#define DP 72            // padded d-stride in ws (f16 elements), 144 B rows

static constexpr size_t CH  = (size_t)HF * WF;
static constexpr size_t WH  = (size_t)HF * WF;
static constexpr float  INV = 1.0f / 576.0f;

typedef _Float16 f16;
typedef _Float16 f16x4 __attribute__((ext_vector_type(4)));
typedef _Float16 f16x8 __attribute__((ext_vector_type(8)));
typedef float    f32x4 __attribute__((ext_vector_type(4)));

#if __has_builtin(__builtin_amdgcn_mfma_f32_16x16x16f16)
#define MFMA16(A, B, C) __builtin_amdgcn_mfma_f32_16x16x16f16((A), (B), (C), 0, 0, 0)
#define FRAG_T f16x4
__device__ __forceinline__ f16x4 mkfrag(f16 a, f16 b, f16 c, f16 d) {
    f16x4 r; r[0] = a; r[1] = b; r[2] = c; r[3] = d; return r;
}
#else
// Fallback: 16x16x32 with upper half of K zeroed on BOTH operands.
#define MFMA16(A, B, C) __builtin_amdgcn_mfma_f32_16x16x32_f16((A), (B), (C), 0, 0, 0)
#define FRAG_T f16x8
__device__ __forceinline__ f16x8 mkfrag(f16 a, f16 b, f16 c, f16 d) {
    f16x8 r; r[0] = a; r[1] = b; r[2] = c; r[3] = d;
    r[4] = (f16)0.f; r[5] = (f16)0.f; r[6] = (f16)0.f; r[7] = (f16)0.f; return r;
}
#endif

// Inline-asm scalar load: SGPR-pair base + 32-bit per-lane byte offset.
#define GLOADF(dst, ptr, offbytes) \
    asm volatile("global_load_dword %0, %1, %2" \
                 : "=v"(dst) : "v"(offbytes), "s"(ptr))

// ---------------------------------------------------------------------------
// k1 (R13): banded Gram via MFMA, fp16 hi/lo (hh+hl+lh), WAVE-AUTONOMOUS,
// DIRECT-FRAGMENT loads + 2-DEEP counted-vmcnt pipeline (T4: never drain 0).
// Each wave owns one (b, y, 32-col strip): no barriers, no K-loop LDS.
// Batch = 32 global_load_dword fetching the iter's fragments directly
// (lane l: col 16*xt+n / clamp(jb+16*jt+n), channels kb+4*kq+i).
// Two batches ping-pong; per-iter wait = s_waitcnt vmcnt(32) so one batch
// is always in flight (~2 compute phases > HBM latency).
// Band mapping d=16p+n-m and epilogue validated R5-R12.
// ---------------------------------------------------------------------------
__global__ __launch_bounds__(256) __attribute__((amdgpu_waves_per_eu(2, 4)))
void corr_gram(const float* __restrict__ x0, const float* __restrict__ x1,
               f16* __restrict__ ws) {
    // XCD swizzle: consecutive tiles of one row on one XCD.
    const int f = blockIdx.x;              // [0, 4096)
    const int tid = (f & 7) * 512 + (f >> 3);
    const int b = tid >> 10;
    const int y = (tid >> 2) & 255;
    const int sg = tid & 3;

    const int t = threadIdx.x;
    const int l = t & 63;
    const int w = t >> 6;
    const int xs = (sg * 4 + w) * 32;      // wave's 32-col strip
    const int jb = xs - 32;

    const int n  = l & 15;                 // fragment row/col
    const int kq = l >> 4;                 // fragment k-quad

    __shared__ f16 ebs[4][2304];           // per-wave epilogue tile (18.4 KB)

    const float* x0r = x0 + (size_t)b * CF * CH + (size_t)y * WF;
    const float* x1r = x1 + (size_t)b * CF * CH + (size_t)y * WF;

    // ---- fragment base byte-offsets (lane-constant) ----
    int aB[2];
#pragma unroll
    for (int xt = 0; xt < 2; ++xt)
        aB[xt] = (4 * kq * (int)CH + xs + 16 * xt + n) * 4;
    int bB[6]; bool okj[6];
#pragma unroll
    for (int jt = 0; jt < 6; ++jt) {
        int col = jb + 16 * jt + n;
        okj[jt] = (unsigned)col < (unsigned)WF;
        col = col < 0 ? 0 : (col > 511 ? 511 : col);   // clamp; zeroed at cvt
        bB[jt] = (4 * kq * (int)CH + col) * 4;
    }

    f32x4 acc[10];
#pragma unroll
    for (int i = 0; i < 10; ++i) acc[i] = (f32x4)0.0f;

    float raA[8], rbA[24], raB[8], rbB[24];

#define ISSUE(kk, RA, RB) do { \
    _Pragma("unroll") for (int xt = 0; xt < 2; ++xt) \
    _Pragma("unroll") for (int i = 0; i < 4; ++i) \
        GLOADF(RA[4*xt+i], x0r, aB[xt] + (16*(kk)+i) * (int)(CH*4)); \
    _Pragma("unroll") for (int jt = 0; jt < 6; ++jt) \
    _Pragma("unroll") for (int i = 0; i < 4; ++i) \
        GLOADF(RB[4*jt+i], x1r, bB[jt] + (16*(kk)+i) * (int)(CH*4)); \
    __builtin_amdgcn_sched_barrier(0); \
} while (0)

#define TRIPLE(ai, AH, AL) do { \
    acc[ai] = MFMA16(AH, bh, acc[ai]); \
    acc[ai] = MFMA16(AH, bl, acc[ai]); \
    acc[ai] = MFMA16(AL, bh, acc[ai]); } while (0)

#define COMPUTE(RA, RB) do { \
    FRAG_T ah[2], al[2]; \
    _Pragma("unroll") for (int xt = 0; xt < 2; ++xt) { \
        const float v0 = RA[4*xt], v1 = RA[4*xt+1], v2 = RA[4*xt+2], v3 = RA[4*xt+3]; \
        const f16 h0 = (f16)v0, h1 = (f16)v1, h2 = (f16)v2, h3 = (f16)v3; \
        ah[xt] = mkfrag(h0, h1, h2, h3); \
        al[xt] = mkfrag((f16)(v0 - (float)h0), (f16)(v1 - (float)h1), \
                        (f16)(v2 - (float)h2), (f16)(v3 - (float)h3)); \
    } \
    _Pragma("unroll") for (int jt = 0; jt < 6; ++jt) { \
        float v0 = RB[4*jt], v1 = RB[4*jt+1], v2 = RB[4*jt+2], v3 = RB[4*jt+3]; \
        v0 = okj[jt] ? v0 : 0.f; v1 = okj[jt] ? v1 : 0.f; \
        v2 = okj[jt] ? v2 : 0.f; v3 = okj[jt] ? v3 : 0.f; \
        const f16 h0 = (f16)v0, h1 = (f16)v1, h2 = (f16)v2, h3 = (f16)v3; \
        const FRAG_T bh = mkfrag(h0, h1, h2, h3); \
        const FRAG_T bl = mkfrag((f16)(v0 - (float)h0), (f16)(v1 - (float)h1), \
                                 (f16)(v2 - (float)h2), (f16)(v3 - (float)h3)); \
        if (jt < 5)  TRIPLE(jt, ah[0], al[0]); \
        if (jt >= 1) TRIPLE(4 + jt, ah[1], al[1]); \
    } \
} while (0)

#define WAIT32() do { asm volatile("s_waitcnt vmcnt(32)" ::: "memory"); \
                      __builtin_amdgcn_sched_barrier(0); } while (0)
#define WAIT0()  do { asm volatile("s_waitcnt vmcnt(0)" ::: "memory"); \
                      __builtin_amdgcn_sched_barrier(0); } while (0)

    ISSUE(0, raA, rbA);
    ISSUE(1, raB, rbB);

    // iter 0: batch0 ready (batch1 in flight); refill buffer A with batch2
    WAIT32();
    COMPUTE(raA, rbA);
    ISSUE(2, raA, rbA);
    // iter 1: batch1 ready (batch2 in flight); refill buffer B with batch3
    WAIT32();
    COMPUTE(raB, rbB);
    ISSUE(3, raB, rbB);
    // iter 2: batch2 ready (batch3 in flight)
    WAIT32();
    COMPUTE(raA, rbA);
    // iter 3: batch3 ready
    WAIT0();
    COMPUTE(raB, rbB);

#undef COMPUTE
#undef TRIPLE
#undef ISSUE
#undef WAIT32
#undef WAIT0

    // ---- epilogue (wave-private): scatter band to LDS, coalesced stores ----
    f16* eb = ebs[w];                      // [32 col][72 d] f16 = 4608 B
#pragma unroll
    for (int xt = 0; xt < 2; ++xt) {
#pragma unroll
        for (int p = 0; p < 5; ++p) {
            const int i = xt * 5 + p;
#pragma unroll
            for (int q = 0; q < 4; ++q) {
                const int m = kq * 4 + q;
                const int xl = xt * 16 + m;
                const int d = 16 * p + n - m;
                if ((unsigned)d < (unsigned)NDTOT)
                    eb[xl * DP + d] = (f16)acc[i][q];
            }
        }
    }
    // zero pad columns d=65..71 (32 x 7 = 224 entries)
#pragma unroll
    for (int i = 0; i < 4; ++i) {
        const int idx = l + 64 * i;
        if (idx < 224) {
            const int xl = idx / 7;
            eb[xl * DP + NDTOT + (idx - 7 * xl)] = (f16)0.f;
        }
    }
    // coalesced store: 32*72 f16 = 4608 B = 288 x 16B chunks
    uint4* dst = (uint4*)(ws + ((size_t)(b * HF + y) * WF + xs) * DP);
    const uint4* src = (const uint4*)eb;
#pragma unroll
    for (int i = 0; i < 5; ++i) {
        const int idx = l + 64 * i;
        if (idx < 288) dst[idx] = src[idx];
    }
}

// ---------------------------------------------------------------------------
// k2: 3x3 box-sum over ws + scale: out[b,d,y,x] = INV * sum_{3x3} ws[y+dy][x+dx][d]
// grid (16 x-tiles of 32, 32 y-tiles of 8, b); 256 thr.
// ---------------------------------------------------------------------------
__global__ __launch_bounds__(256)
void corr_box(const f16* __restrict__ ws, float* __restrict__ out) {
    const int xt = blockIdx.x;
    const int yt = blockIdx.y;
    const int b = blockIdx.z;
    const int t = threadIdx.x;
    const int x0b = xt * 32, y0 = yt * 8;

    __shared__ f16 S[10 * 34][DP];     // 48.96 KB

    for (int u = 0; u < 10; ++u) {
        const int yy = y0 - 1 + u;
        const bool yok = (unsigned)yy < (unsigned)HF;
        const f16* src = ws + ((size_t)(b * HF + yy) * WF + (x0b - 1)) * DP;
#pragma unroll
        for (int sub = 0; sub < 2; ++sub) {
            const int idx = sub * 256 + t;
            if (idx < 306) {
                const int v = idx / 9, dg = idx - v * 9;
                const int xx = x0b - 1 + v;
                f16x8 val;
#pragma unroll
                for (int jj = 0; jj < 8; ++jj) val[jj] = (f16)0.f;
                if (yok && (unsigned)xx < (unsigned)WF)
                    val = *(const f16x8*)(src + (size_t)v * DP + dg * 8);
                *(f16x8*)&S[u * 34 + v][dg * 8] = val;
            }
        }
    }
    __syncthreads();

    const int ly = t >> 5, lx = t & 31;
    const int yg = y0 + ly, xg = x0b + lx;
    float* o0 = out + (size_t)b * NDTOT * WH + (size_t)yg * WF + xg;

#pragma unroll 1
    for (int dg = 0; dg < 9; ++dg) {
        f16x8 s;
#pragma unroll
        for (int jj = 0; jj < 8; ++jj) s[jj] = (f16)0.f;
#pragma unroll
        for (int du = 0; du < 3; ++du)
#pragma unroll
            for (int dv = 0; dv < 3; ++dv)
                s += *(const f16x8*)&S[(ly + du) * 34 + (lx + dv)][dg * 8];
#pragma unroll
        for (int jj = 0; jj < 8; ++jj) {
            const int d = dg * 8 + jj;
            if (d < NDTOT) o0[(size_t)d * WH] = (float)s[jj] * INV;
        }
    }
}

// ---------------------------------------------------------------------------
// Emergency fallback (tiny ws): direct computation, slow but correct.
// ---------------------------------------------------------------------------
__global__ void corr_naive(const float* __restrict__ x0, const float* __restrict__ x1,
                           float* __restrict__ out) {
    const size_t total = (size_t)4 * NDTOT * WH;
    size_t idx = (size_t)blockIdx.x * blockDim.x + threadIdx.x;
    if (idx >= total) return;
    const int j = (int)(idx % WF);
    const int i = (int)((idx / WF) % HF);
    const int d = (int)((idx / WH) % NDTOT);
    const int b = (int)(idx / ((size_t)NDTOT * WH));
    const int disp = d - 32;
    float s = 0.f;
    for (int u = i - 1; u <= i + 1; ++u) {
        if (u < 0 || u >= HF) continue;
        for (int v = j - 1; v <= j + 1; ++v) {
            if (v < 0 || v >= WF) continue;
            const int v1c = v + disp;
            if (v1c < 0 || v1c >= WF) continue;
            const float* p0 = x0 + (size_t)b * CF * CH + (size_t)u * WF + v;
            const float* p1 = x1 + (size_t)b * CF * CH + (size_t)u * WF + v1c;
            for (int c = 0; c < CF; ++c)
                s += p0[(size_t)c * CH] * p1[(size_t)c * CH];
        }
    }
    out[idx] = s * INV;
}

// ---------------------------------------------------------------------------
extern "C" void kernel_launch(void* const* d_in, const int* in_sizes, int n_in,
                              void* d_out, int out_size, void* d_ws, size_t ws_size,
                              hipStream_t stream) {
    const float* x0 = (const float*)d_in[0];
    const float* x1 = (const float*)d_in[1];
    float* out = (float*)d_out;

    const size_t wsNeed = (size_t)4 * HF * WF * DP * sizeof(f16);  // 75.5 MB

    if (ws_size >= wsNeed) {
        f16* ws = (f16*)d_ws;
        corr_gram<<<dim3(4096), dim3(256), 0, stream>>>(x0, x1, ws);
        corr_box<<<dim3(16, 32, 4), dim3(256), 0, stream>>>(ws, out);
    } else {
        const size_t total = (size_t)4 * NDTOT * WH;
        const int blocks = (int)((total + 255) / 256);
        corr_naive<<<dim3(blocks), dim3(256), 0, stream>>>(x0, x1, out);
    }
}

// Round 14
// 133.004 us; speedup vs baseline: 1.0006x; 1.0006x over previous
//
#include <hip/hip_runtime.h>

#define WF 512
#define HF 256
#define CF 64
#define NDTOT 65
#define DP 72            // padded d-stride in ws (f16 elements), 144 B rows

static constexpr size_t CH  = (size_t)HF * WF;
static constexpr size_t WH  = (size_t)HF * WF;
static constexpr float  INV = 1.0f / 576.0f;

typedef _Float16 f16;
typedef _Float16 f16x4 __attribute__((ext_vector_type(4)));
typedef _Float16 f16x8 __attribute__((ext_vector_type(8)));
typedef float    f32x4 __attribute__((ext_vector_type(4)));

#if __has_builtin(__builtin_amdgcn_mfma_f32_16x16x16f16)
#define MFMA16(A, B, C) __builtin_amdgcn_mfma_f32_16x16x16f16((A), (B), (C), 0, 0, 0)
#define FRAG_T f16x4
__device__ __forceinline__ f16x4 mkfrag(f16 a, f16 b, f16 c, f16 d) {
    f16x4 r; r[0] = a; r[1] = b; r[2] = c; r[3] = d; return r;
}
#else
#define MFMA16(A, B, C) __builtin_amdgcn_mfma_f32_16x16x32_f16((A), (B), (C), 0, 0, 0)
#define FRAG_T f16x8
__device__ __forceinline__ f16x8 mkfrag(f16 a, f16 b, f16 c, f16 d) {
    f16x8 r; r[0] = a; r[1] = b; r[2] = c; r[3] = d;
    r[4] = (f16)0.f; r[5] = (f16)0.f; r[6] = (f16)0.f; r[7] = (f16)0.f; return r;
}
#endif

// Inline-asm scalar load: SGPR-pair base + 32-bit per-lane byte offset.
#define GLOADF(dst, ptr, offbytes) \
    asm volatile("global_load_dword %0, %1, %2" \
                 : "=v"(dst) : "v"(offbytes), "s"(ptr))

// ---------------------------------------------------------------------------
// k1 (R14): banded Gram via MFMA, fp16 hi/lo (hh+hl+lh), WAVE-AUTONOMOUS,
// DIRECT-FRAGMENT loads with a 7-DEEP SUB-BATCH PIPELINE (T4, counted vmcnt).
// 16 sub-batches of 8 loads (4 iters x {A, Bjt01, Bjt23, Bjt45}); steady
// state keeps 7 sub-batches (56 loads) in flight; waits are vmcnt(48) then
// a counted tail 40->0. Ring of 8 static register octets (bufs[8][8]).
// Band mapping d=16p+n-m, frag layout, epilogue: validated R5-R13.
// ---------------------------------------------------------------------------
__global__ __launch_bounds__(256) __attribute__((amdgpu_waves_per_eu(3)))
void corr_gram(const float* __restrict__ x0, const float* __restrict__ x1,
               f16* __restrict__ ws) {
    // XCD swizzle: consecutive tiles of one row on one XCD.
    const int f = blockIdx.x;              // [0, 4096)
    const int tid = (f & 7) * 512 + (f >> 3);
    const int b = tid >> 10;
    const int y = (tid >> 2) & 255;
    const int sg = tid & 3;

    const int t = threadIdx.x;
    const int l = t & 63;
    const int w = t >> 6;
    const int xs = (sg * 4 + w) * 32;      // wave's 32-col strip
    const int jb = xs - 32;

    const int n  = l & 15;                 // fragment row/col
    const int kq = l >> 4;                 // fragment k-quad

    __shared__ f16 ebs[4][2304];           // per-wave epilogue tile (18.4 KB)

    const float* x0r = x0 + (size_t)b * CF * CH + (size_t)y * WF;
    const float* x1r = x1 + (size_t)b * CF * CH + (size_t)y * WF;

    // ---- fragment base byte-offsets (lane-constant), validated R13 ----
    int aB[2];
#pragma unroll
    for (int xt = 0; xt < 2; ++xt)
        aB[xt] = (4 * kq * (int)CH + xs + 16 * xt + n) * 4;
    int bB[6]; bool okj[6];
#pragma unroll
    for (int jt = 0; jt < 6; ++jt) {
        int col = jb + 16 * jt + n;
        okj[jt] = (unsigned)col < (unsigned)WF;
        col = col < 0 ? 0 : (col > 511 ? 511 : col);   // clamp; zeroed at cvt
        bB[jt] = (4 * kq * (int)CH + col) * 4;
    }

    f32x4 acc[10];
#pragma unroll
    for (int i = 0; i < 10; ++i) acc[i] = (f32x4)0.0f;

    float bufs[8][8];                      // ring of 8 static register octets
    FRAG_T ah0, ah1, al0, al1;

#define ISS_A(kk, B) do { \
    _Pragma("unroll") for (int xt = 0; xt < 2; ++xt) \
    _Pragma("unroll") for (int i = 0; i < 4; ++i) \
        GLOADF(bufs[B][4*xt+i], x0r, aB[xt] + (16*(kk)+i) * (int)(CH*4)); \
    __builtin_amdgcn_sched_barrier(0); \
} while (0)

#define ISS_B(kk, p, B) do { \
    _Pragma("unroll") for (int u = 0; u < 2; ++u) \
    _Pragma("unroll") for (int i = 0; i < 4; ++i) \
        GLOADF(bufs[B][4*u+i], x1r, bB[2*((p)-1)+u] + (16*(kk)+i) * (int)(CH*4)); \
    __builtin_amdgcn_sched_barrier(0); \
} while (0)

#define WAITN(N) do { asm volatile("s_waitcnt vmcnt(" #N ")" ::: "memory"); \
                      __builtin_amdgcn_sched_barrier(0); } while (0)

#define TRIPLE(ai, AH, AL) do { \
    acc[ai] = MFMA16(AH, bh, acc[ai]); \
    acc[ai] = MFMA16(AH, bl, acc[ai]); \
    acc[ai] = MFMA16(AL, bh, acc[ai]); } while (0)

#define CON_A(B) do { \
    { const float v0 = bufs[B][0], v1 = bufs[B][1], v2 = bufs[B][2], v3 = bufs[B][3]; \
      const f16 h0 = (f16)v0, h1 = (f16)v1, h2 = (f16)v2, h3 = (f16)v3; \
      ah0 = mkfrag(h0, h1, h2, h3); \
      al0 = mkfrag((f16)(v0-(float)h0), (f16)(v1-(float)h1), (f16)(v2-(float)h2), (f16)(v3-(float)h3)); } \
    { const float v0 = bufs[B][4], v1 = bufs[B][5], v2 = bufs[B][6], v3 = bufs[B][7]; \
      const f16 h0 = (f16)v0, h1 = (f16)v1, h2 = (f16)v2, h3 = (f16)v3; \
      ah1 = mkfrag(h0, h1, h2, h3); \
      al1 = mkfrag((f16)(v0-(float)h0), (f16)(v1-(float)h1), (f16)(v2-(float)h2), (f16)(v3-(float)h3)); } \
} while (0)

#define CON_B(p, B) do { \
    _Pragma("unroll") for (int u = 0; u < 2; ++u) { \
        const int jt = 2*((p)-1) + u; \
        float v0 = bufs[B][4*u], v1 = bufs[B][4*u+1], v2 = bufs[B][4*u+2], v3 = bufs[B][4*u+3]; \
        v0 = okj[jt] ? v0 : 0.f; v1 = okj[jt] ? v1 : 0.f; \
        v2 = okj[jt] ? v2 : 0.f; v3 = okj[jt] ? v3 : 0.f; \
        const f16 h0 = (f16)v0, h1 = (f16)v1, h2 = (f16)v2, h3 = (f16)v3; \
        const FRAG_T bh = mkfrag(h0, h1, h2, h3); \
        const FRAG_T bl = mkfrag((f16)(v0-(float)h0), (f16)(v1-(float)h1), \
                                 (f16)(v2-(float)h2), (f16)(v3-(float)h3)); \
        if (jt < 5)  TRIPLE(jt, ah0, al0); \
        if (jt >= 1) TRIPLE(4 + jt, ah1, al1); \
    } \
} while (0)

    // ---- prologue: 7 sub-batches in flight (56 loads) ----
    ISS_A(0, 0); ISS_B(0, 1, 1); ISS_B(0, 2, 2); ISS_B(0, 3, 3);
    ISS_A(1, 4); ISS_B(1, 1, 5); ISS_B(1, 2, 6);

    // ---- 16 sub-phases: wait(counted) -> issue s+7 -> consume s ----
    WAITN(48); ISS_B(1, 3, 7); CON_A(0);        // s=0
    WAITN(48); ISS_A(2, 0);    CON_B(1, 1);     // s=1
    WAITN(48); ISS_B(2, 1, 1); CON_B(2, 2);     // s=2
    WAITN(48); ISS_B(2, 2, 2); CON_B(3, 3);     // s=3
    WAITN(48); ISS_B(2, 3, 3); CON_A(4);        // s=4
    WAITN(48); ISS_A(3, 4);    CON_B(1, 5);     // s=5
    WAITN(48); ISS_B(3, 1, 5); CON_B(2, 6);     // s=6
    WAITN(48); ISS_B(3, 2, 6); CON_B(3, 7);     // s=7
    WAITN(48); ISS_B(3, 3, 7); CON_A(0);        // s=8
    WAITN(48); CON_B(1, 1);                     // s=9
    WAITN(40); CON_B(2, 2);                     // s=10
    WAITN(32); CON_B(3, 3);                     // s=11
    WAITN(24); CON_A(4);                        // s=12
    WAITN(16); CON_B(1, 5);                     // s=13
    WAITN(8);  CON_B(2, 6);                     // s=14
    WAITN(0);  CON_B(3, 7);                     // s=15

#undef CON_B
#undef CON_A
#undef TRIPLE
#undef WAITN
#undef ISS_B
#undef ISS_A

    // ---- epilogue (wave-private): scatter band to LDS, coalesced stores ----
    f16* eb = ebs[w];                      // [32 col][72 d] f16 = 4608 B
#pragma unroll
    for (int xt = 0; xt < 2; ++xt) {
#pragma unroll
        for (int p = 0; p < 5; ++p) {
            const int i = xt * 5 + p;
#pragma unroll
            for (int q = 0; q < 4; ++q) {
                const int m = kq * 4 + q;
                const int xl = xt * 16 + m;
                const int d = 16 * p + n - m;
                if ((unsigned)d < (unsigned)NDTOT)
                    eb[xl * DP + d] = (f16)acc[i][q];
            }
        }
    }
    // zero pad columns d=65..71 (32 x 7 = 224 entries)
#pragma unroll
    for (int i = 0; i < 4; ++i) {
        const int idx = l + 64 * i;
        if (idx < 224) {
            const int xl = idx / 7;
            eb[xl * DP + NDTOT + (idx - 7 * xl)] = (f16)0.f;
        }
    }
    // coalesced store: 32*72 f16 = 4608 B = 288 x 16B chunks
    uint4* dst = (uint4*)(ws + ((size_t)(b * HF + y) * WF + xs) * DP);
    const uint4* src = (const uint4*)eb;
#pragma unroll
    for (int i = 0; i < 5; ++i) {
        const int idx = l + 64 * i;
        if (idx < 288) dst[idx] = src[idx];
    }
}

// ---------------------------------------------------------------------------
// k2: 3x3 box-sum over ws + scale: out[b,d,y,x] = INV * sum_{3x3} ws[y+dy][x+dx][d]
// grid (16 x-tiles of 32, 32 y-tiles of 8, b); 256 thr.
// ---------------------------------------------------------------------------
__global__ __launch_bounds__(256)
void corr_box(const f16* __restrict__ ws, float* __restrict__ out) {
    const int xt = blockIdx.x;
    const int yt = blockIdx.y;
    const int b = blockIdx.z;
    const int t = threadIdx.x;
    const int x0b = xt * 32, y0 = yt * 8;

    __shared__ f16 S[10 * 34][DP];     // 48.96 KB

    for (int u = 0; u < 10; ++u) {
        const int yy = y0 - 1 + u;
        const bool yok = (unsigned)yy < (unsigned)HF;
        const f16* src = ws + ((size_t)(b * HF + yy) * WF + (x0b - 1)) * DP;
#pragma unroll
        for (int sub = 0; sub < 2; ++sub) {
            const int idx = sub * 256 + t;
            if (idx < 306) {
                const int v = idx / 9, dg = idx - v * 9;
                const int xx = x0b - 1 + v;
                f16x8 val;
#pragma unroll
                for (int jj = 0; jj < 8; ++jj) val[jj] = (f16)0.f;
                if (yok && (unsigned)xx < (unsigned)WF)
                    val = *(const f16x8*)(src + (size_t)v * DP + dg * 8);
                *(f16x8*)&S[u * 34 + v][dg * 8] = val;
            }
        }
    }
    __syncthreads();

    const int ly = t >> 5, lx = t & 31;
    const int yg = y0 + ly, xg = x0b + lx;
    float* o0 = out + (size_t)b * NDTOT * WH + (size_t)yg * WF + xg;

#pragma unroll 1
    for (int dg = 0; dg < 9; ++dg) {
        f16x8 s;
#pragma unroll
        for (int jj = 0; jj < 8; ++jj) s[jj] = (f16)0.f;
#pragma unroll
        for (int du = 0; du < 3; ++du)
#pragma unroll
            for (int dv = 0; dv < 3; ++dv)
                s += *(const f16x8*)&S[(ly + du) * 34 + (lx + dv)][dg * 8];
#pragma unroll
        for (int jj = 0; jj < 8; ++jj) {
            const int d = dg * 8 + jj;
            if (d < NDTOT) o0[(size_t)d * WH] = (float)s[jj] * INV;
        }
    }
}

// ---------------------------------------------------------------------------
// Emergency fallback (tiny ws): direct computation, slow but correct.
// ---------------------------------------------------------------------------
__global__ void corr_naive(const float* __restrict__ x0, const float* __restrict__ x1,
                           float* __restrict__ out) {
    const size_t total = (size_t)4 * NDTOT * WH;
    size_t idx = (size_t)blockIdx.x * blockDim.x + threadIdx.x;
    if (idx >= total) return;
    const int j = (int)(idx % WF);
    const int i = (int)((idx / WF) % HF);
    const int d = (int)((idx / WH) % NDTOT);
    const int b = (int)(idx / ((size_t)NDTOT * WH));
    const int disp = d - 32;
    float s = 0.f;
    for (int u = i - 1; u <= i + 1; ++u) {
        if (u < 0 || u >= HF) continue;
        for (int v = j - 1; v <= j + 1; ++v) {
            if (v < 0 || v >= WF) continue;
            const int v1c = v + disp;
            if (v1c < 0 || v1c >= WF) continue;
            const float* p0 = x0 + (size_t)b * CF * CH + (size_t)u * WF + v;
            const float* p1 = x1 + (size_t)b * CF * CH + (size_t)u * WF + v1c;
            for (int c = 0; c < CF; ++c)
                s += p0[(size_t)c * CH] * p1[(size_t)c * CH];
        }
    }
    out[idx] = s * INV;
}

// ---------------------------------------------------------------------------
extern "C" void kernel_launch(void* const* d_in, const int* in_sizes, int n_in,
                              void* d_out, int out_size, void* d_ws, size_t ws_size,
                              hipStream_t stream) {
    const float* x0 = (const float*)d_in[0];
    const float* x1 = (const float*)d_in[1];
    float* out = (float*)d_out;

    const size_t wsNeed = (size_t)4 * HF * WF * DP * sizeof(f16);  // 75.5 MB

    if (ws_size >= wsNeed) {
        f16* ws = (f16*)d_ws;
        corr_gram<<<dim3(4096), dim3(256), 0, stream>>>(x0, x1, ws);
        corr_box<<<dim3(16, 32, 4), dim3(256), 0, stream>>>(ws, out);
    } else {
        const size_t total = (size_t)4 * NDTOT * WH;
        const int blocks = (int)((total + 255) / 256);
        corr_naive<<<dim3(blocks), dim3(256), 0, stream>>>(x0, x1, out);
    }
}

// Round 15
// 128.802 us; speedup vs baseline: 1.0332x; 1.0326x over previous
//
#include <hip/hip_runtime.h>

#define WF 512
#define HF 256
#define CF 64
#define NDTOT 65
#define DP 72            // padded d-stride in ws (f16 elements), 144 B rows

static constexpr size_t CH  = (size_t)HF * WF;
static constexpr size_t WH  = (size_t)HF * WF;
static constexpr float  INV = 1.0f / 576.0f;

typedef _Float16 f16;
typedef _Float16 f16x4 __attribute__((ext_vector_type(4)));
typedef _Float16 f16x8 __attribute__((ext_vector_type(8)));
typedef float    f32x4 __attribute__((ext_vector_type(4)));

typedef __attribute__((address_space(3))) void lds_void_t;
typedef const __attribute__((address_space(1))) void glb_void_t;

#if __has_builtin(__builtin_amdgcn_mfma_f32_16x16x16f16)
#define MFMA16(A, B, C) __builtin_amdgcn_mfma_f32_16x16x16f16((A), (B), (C), 0, 0, 0)
#define FRAG_T f16x4
__device__ __forceinline__ f16x4 mkfrag(f16 a, f16 b, f16 c, f16 d) {
    f16x4 r; r[0] = a; r[1] = b; r[2] = c; r[3] = d; return r;
}
#else
#define MFMA16(A, B, C) __builtin_amdgcn_mfma_f32_16x16x32_f16((A), (B), (C), 0, 0, 0)
#define FRAG_T f16x8
__device__ __forceinline__ f16x8 mkfrag(f16 a, f16 b, f16 c, f16 d) {
    f16x8 r; r[0] = a; r[1] = b; r[2] = c; r[3] = d;
    r[4] = (f16)0.f; r[5] = (f16)0.f; r[6] = (f16)0.f; r[7] = (f16)0.f; return r;
}
#endif

// ---------------------------------------------------------------------------
// k1 (R15): banded Gram via MFMA, fp16 hi/lo (hh+hl+lh), WAVE-AUTONOMOUS,
// x-major LDS staging via 8 fat global_load_lds per K-iter (16 ch):
//   A: 16ch x 32col f32  (2 instrs, 2 KB)   B: 16ch x 96col f32 (6 instrs, 6 KB)
// single 8 KB wave-private buffer; vmcnt(0) at iter top (loads issued one
// full compute phase earlier); 32 ds_read_b32 per iter off 2 address regs +
// compile-time offsets; lgkmcnt(0) then issue next iter's loads (overwrite
// safe); cvt f16 hi/lo + 90 MFMAs overlap the loads. No barriers anywhere.
// VMEM instrs/wave: 32 (was 512 in R13). Regs: ~70 VGPR + 40 AGPR.
// Band mapping d=16p+n-m, frag layout, epilogue: validated R5-R14.
// ---------------------------------------------------------------------------
__global__ __launch_bounds__(256) __attribute__((amdgpu_waves_per_eu(4, 8)))
void corr_gram(const float* __restrict__ x0, const float* __restrict__ x1,
               f16* __restrict__ ws) {
    // XCD swizzle: consecutive tiles of one row on one XCD.
    const int f = blockIdx.x;              // [0, 4096)
    const int tid = (f & 7) * 512 + (f >> 3);
    const int b = tid >> 10;
    const int y = (tid >> 2) & 255;
    const int sg = tid & 3;

    const int t = threadIdx.x;
    const int l = t & 63;
    const int w = t >> 6;
    const int xs = (sg * 4 + w) * 32;      // wave's 32-col strip
    const int jb = xs - 32;

    const int n  = l & 15;                 // fragment row/col
    const int kq = l >> 4;                 // fragment k-quad

    __shared__ float lds[8192];            // 32 KB; 2048 floats per wave
    const int wbase = w * 2048;            // A: [0,512), B: [512,2048) floats

    const float* x0r = x0 + (size_t)b * CF * CH + (size_t)y * WF;
    const float* x1r = x1 + (size_t)b * CF * CH + (size_t)y * WF;

    // ---- gl_lds per-lane SOURCE offsets (floats, lane-constant) ----
    // A instr i: granule P = i*64+l -> ch = P>>3, c4 = l&7
    const int offA0 = (l >> 3) * (int)CH + xs + 4 * (l & 7);
    const int offA1 = offA0 + 8 * (int)CH;
    // B instr r: P = r*64+l -> ch = P/24, rem = P%24, col = clamp(jb+4*rem)
    int offB[6];
#pragma unroll
    for (int r = 0; r < 6; ++r) {
        const int P = r * 64 + l;
        const int ch = P / 24;
        const int rem = P - 24 * ch;
        int col = jb + 4 * rem;
        col = col < 0 ? 0 : (col > 508 ? 508 : col);   // clamp; zeroed at cvt
        offB[r] = ch * (int)CH + col;
    }

    // ---- frag ds_read base regs (floats); element offsets compile-time ----
    const int fA = wbase + kq * 128 + n;           // + i*32 + xt*16
    const int fB = wbase + 512 + kq * 384 + n;     // + i*96 + jt*16

    bool okj[6];
#pragma unroll
    for (int jt = 0; jt < 6; ++jt) okj[jt] = (unsigned)(jb + 16 * jt + n) < (unsigned)WF;

    f32x4 acc[10];
#pragma unroll
    for (int i = 0; i < 10; ++i) acc[i] = (f32x4)0.0f;

#define ISSUE(kk) do { \
    const float* x0k = x0r + (size_t)(kk) * 16 * CH; \
    const float* x1k = x1r + (size_t)(kk) * 16 * CH; \
    __builtin_amdgcn_global_load_lds((glb_void_t*)(x0k + offA0), (lds_void_t*)(lds + wbase),       16, 0, 0); \
    __builtin_amdgcn_global_load_lds((glb_void_t*)(x0k + offA1), (lds_void_t*)(lds + wbase + 256), 16, 0, 0); \
    _Pragma("unroll") \
    for (int r = 0; r < 6; ++r) \
        __builtin_amdgcn_global_load_lds((glb_void_t*)(x1k + offB[r]), \
            (lds_void_t*)(lds + wbase + 512 + r * 256), 16, 0, 0); \
} while (0)

#define TRIPLE(ai, AH, AL) do { \
    acc[ai] = MFMA16(AH, bh, acc[ai]); \
    acc[ai] = MFMA16(AH, bl, acc[ai]); \
    acc[ai] = MFMA16(AL, bh, acc[ai]); } while (0)

#define COMPUTE(kk) do { \
    asm volatile("s_waitcnt vmcnt(0)" ::: "memory"); \
    __builtin_amdgcn_sched_barrier(0); \
    float fa[2][4], fb[6][4]; \
    _Pragma("unroll") \
    for (int xt = 0; xt < 2; ++xt) \
    _Pragma("unroll") \
    for (int i = 0; i < 4; ++i) fa[xt][i] = lds[fA + i * 32 + xt * 16]; \
    _Pragma("unroll") \
    for (int jt = 0; jt < 6; ++jt) \
    _Pragma("unroll") \
    for (int i = 0; i < 4; ++i) fb[jt][i] = lds[fB + i * 96 + jt * 16]; \
    asm volatile("s_waitcnt lgkmcnt(0)" ::: "memory"); \
    __builtin_amdgcn_sched_barrier(0); \
    if ((kk) < 3) ISSUE((kk) + 1); \
    __builtin_amdgcn_sched_barrier(0); \
    FRAG_T ah0, al0, ah1, al1; \
    { const float v0 = fa[0][0], v1 = fa[0][1], v2 = fa[0][2], v3 = fa[0][3]; \
      const f16 h0 = (f16)v0, h1 = (f16)v1, h2 = (f16)v2, h3 = (f16)v3; \
      ah0 = mkfrag(h0, h1, h2, h3); \
      al0 = mkfrag((f16)(v0-(float)h0), (f16)(v1-(float)h1), (f16)(v2-(float)h2), (f16)(v3-(float)h3)); } \
    { const float v0 = fa[1][0], v1 = fa[1][1], v2 = fa[1][2], v3 = fa[1][3]; \
      const f16 h0 = (f16)v0, h1 = (f16)v1, h2 = (f16)v2, h3 = (f16)v3; \
      ah1 = mkfrag(h0, h1, h2, h3); \
      al1 = mkfrag((f16)(v0-(float)h0), (f16)(v1-(float)h1), (f16)(v2-(float)h2), (f16)(v3-(float)h3)); } \
    _Pragma("unroll") \
    for (int jt = 0; jt < 6; ++jt) { \
        float v0 = fb[jt][0], v1 = fb[jt][1], v2 = fb[jt][2], v3 = fb[jt][3]; \
        v0 = okj[jt] ? v0 : 0.f; v1 = okj[jt] ? v1 : 0.f; \
        v2 = okj[jt] ? v2 : 0.f; v3 = okj[jt] ? v3 : 0.f; \
        const f16 h0 = (f16)v0, h1 = (f16)v1, h2 = (f16)v2, h3 = (f16)v3; \
        const FRAG_T bh = mkfrag(h0, h1, h2, h3); \
        const FRAG_T bl = mkfrag((f16)(v0-(float)h0), (f16)(v1-(float)h1), \
                                 (f16)(v2-(float)h2), (f16)(v3-(float)h3)); \
        if (jt < 5)  TRIPLE(jt, ah0, al0); \
        if (jt >= 1) TRIPLE(4 + jt, ah1, al1); \
    } \
} while (0)

    ISSUE(0);
    COMPUTE(0);
    COMPUTE(1);
    COMPUTE(2);
    COMPUTE(3);

#undef COMPUTE
#undef TRIPLE
#undef ISSUE

    // ---- epilogue (wave-private): scatter band into the staging region ----
    f16* eb = (f16*)(lds + wbase);         // [32 col][72 d] f16 = 4608 B
#pragma unroll
    for (int xt = 0; xt < 2; ++xt) {
#pragma unroll
        for (int p = 0; p < 5; ++p) {
            const int i = xt * 5 + p;
#pragma unroll
            for (int q = 0; q < 4; ++q) {
                const int m = kq * 4 + q;
                const int xl = xt * 16 + m;
                const int d = 16 * p + n - m;
                if ((unsigned)d < (unsigned)NDTOT)
                    eb[xl * DP + d] = (f16)acc[i][q];
            }
        }
    }
    // zero pad columns d=65..71 (32 x 7 = 224 entries)
#pragma unroll
    for (int i = 0; i < 4; ++i) {
        const int idx = l + 64 * i;
        if (idx < 224) {
            const int xl = idx / 7;
            eb[xl * DP + NDTOT + (idx - 7 * xl)] = (f16)0.f;
        }
    }
    // coalesced store: 32*72 f16 = 4608 B = 288 x 16B chunks
    uint4* dst = (uint4*)(ws + ((size_t)(b * HF + y) * WF + xs) * DP);
    const uint4* src = (const uint4*)eb;
#pragma unroll
    for (int i = 0; i < 5; ++i) {
        const int idx = l + 64 * i;
        if (idx < 288) dst[idx] = src[idx];
    }
}

// ---------------------------------------------------------------------------
// k2: 3x3 box-sum over ws + scale: out[b,d,y,x] = INV * sum_{3x3} ws[y+dy][x+dx][d]
// grid (16 x-tiles of 32, 32 y-tiles of 8, b); 256 thr.
// ---------------------------------------------------------------------------
__global__ __launch_bounds__(256)
void corr_box(const f16* __restrict__ ws, float* __restrict__ out) {
    const int xt = blockIdx.x;
    const int yt = blockIdx.y;
    const int b = blockIdx.z;
    const int t = threadIdx.x;
    const int x0b = xt * 32, y0 = yt * 8;

    __shared__ f16 S[10 * 34][DP];     // 48.96 KB

    for (int u = 0; u < 10; ++u) {
        const int yy = y0 - 1 + u;
        const bool yok = (unsigned)yy < (unsigned)HF;
        const f16* src = ws + ((size_t)(b * HF + yy) * WF + (x0b - 1)) * DP;
#pragma unroll
        for (int sub = 0; sub < 2; ++sub) {
            const int idx = sub * 256 + t;
            if (idx < 306) {
                const int v = idx / 9, dg = idx - v * 9;
                const int xx = x0b - 1 + v;
                f16x8 val;
#pragma unroll
                for (int jj = 0; jj < 8; ++jj) val[jj] = (f16)0.f;
                if (yok && (unsigned)xx < (unsigned)WF)
                    val = *(const f16x8*)(src + (size_t)v * DP + dg * 8);
                *(f16x8*)&S[u * 34 + v][dg * 8] = val;
            }
        }
    }
    __syncthreads();

    const int ly = t >> 5, lx = t & 31;
    const int yg = y0 + ly, xg = x0b + lx;
    float* o0 = out + (size_t)b * NDTOT * WH + (size_t)yg * WF + xg;

#pragma unroll 1
    for (int dg = 0; dg < 9; ++dg) {
        f16x8 s;
#pragma unroll
        for (int jj = 0; jj < 8; ++jj) s[jj] = (f16)0.f;
#pragma unroll
        for (int du = 0; du < 3; ++du)
#pragma unroll
            for (int dv = 0; dv < 3; ++dv)
                s += *(const f16x8*)&S[(ly + du) * 34 + (lx + dv)][dg * 8];
#pragma unroll
        for (int jj = 0; jj < 8; ++jj) {
            const int d = dg * 8 + jj;
            if (d < NDTOT) o0[(size_t)d * WH] = (float)s[jj] * INV;
        }
    }
}

// ---------------------------------------------------------------------------
// Emergency fallback (tiny ws): direct computation, slow but correct.
// ---------------------------------------------------------------------------
__global__ void corr_naive(const float* __restrict__ x0, const float* __restrict__ x1,
                           float* __restrict__ out) {
    const size_t total = (size_t)4 * NDTOT * WH;
    size_t idx = (size_t)blockIdx.x * blockDim.x + threadIdx.x;
    if (idx >= total) return;
    const int j = (int)(idx % WF);
    const int i = (int)((idx / WF) % HF);
    const int d = (int)((idx / WH) % NDTOT);
    const int b = (int)(idx / ((size_t)NDTOT * WH));
    const int disp = d - 32;
    float s = 0.f;
    for (int u = i - 1; u <= i + 1; ++u) {
        if (u < 0 || u >= HF) continue;
        for (int v = j - 1; v <= j + 1; ++v) {
            if (v < 0 || v >= WF) continue;
            const int v1c = v + disp;
            if (v1c < 0 || v1c >= WF) continue;
            const float* p0 = x0 + (size_t)b * CF * CH + (size_t)u * WF + v;
            const float* p1 = x1 + (size_t)b * CF * CH + (size_t)u * WF + v1c;
            for (int c = 0; c < CF; ++c)
                s += p0[(size_t)c * CH] * p1[(size_t)c * CH];
        }
    }
    out[idx] = s * INV;
}

// ---------------------------------------------------------------------------
extern "C" void kernel_launch(void* const* d_in, const int* in_sizes, int n_in,
                              void* d_out, int out_size, void* d_ws, size_t ws_size,
                              hipStream_t stream) {
    const float* x0 = (const float*)d_in[0];
    const float* x1 = (const float*)d_in[1];
    float* out = (float*)d_out;

    const size_t wsNeed = (size_t)4 * HF * WF * DP * sizeof(f16);  // 75.5 MB

    if (ws_size >= wsNeed) {
        f16* ws = (f16*)d_ws;
        corr_gram<<<dim3(4096), dim3(256), 0, stream>>>(x0, x1, ws);
        corr_box<<<dim3(16, 32, 4), dim3(256), 0, stream>>>(ws, out);
    } else {
        const size_t total = (size_t)4 * NDTOT * WH;
        const int blocks = (int)((total + 255) / 256);
        corr_naive<<<dim3(blocks), dim3(256), 0, stream>>>(x0, x1, out);
    }
}